// Round 14
// baseline (984.441 us; speedup 1.0000x reference)
//
#include <hip/hip_runtime.h>

// ResidualVectorQuantizer — bit-exact replication of the harness's f32 numpy ref.
// dist = np.sum(r*r,-1,keepdims) + np.sum(c*c,-1) - 2*np.einsum('btd,kd->btk',r,c)
//
// Model (the unique combination consistent with all 13 rounds of fingerprints):
//   np.sum n=8 (column-sweep sequential):
//     s = ((((((p0+p1)+p2)+p3)+p4)+p5)+p6)+p7,  p_i = fl(x_i*x_i)
//   np.einsum (C-SOP, SSE3 baseline, no FMA): vstep=4, 2 iters:
//     l_i = fl(m_i + m_{i+4}),  m_i = fl(r_i*c_i)
//     dot = (l0+l1) + (l2+l3)          [_mm_hadd_ps x2]
//   dist = fl(fl(rr+cc) - fl(2*dot)); argmin = first min (strict <).
// Updates: exactly-rounded f32 elementwise (matches numpy given same codes).

#define TOKENS   262144      // B*T
#define D        8
#define K        1024
#define Q        8
#define LOSS_OFF 2097152
#define CODES_OFF 2097153

#define BLK      256
#define TPT      2
#define GRID     (TOKENS / (BLK * TPT))   // 512 blocks

// pure sequential sum of 8 (column-sweep reduce)
__device__ __forceinline__ float np_sum8_pureseq(const float* __restrict__ p) {
#pragma clang fp contract(off)
  float s = p[0];
  s = s + p[1]; s = s + p[2]; s = s + p[3]; s = s + p[4];
  s = s + p[5]; s = s + p[6]; s = s + p[7];
  return s;
}

// ---- prep: cc[q*K+k] = np.sum(c*c, -1) ----
__global__ __launch_bounds__(BLK) void rvq_prep(const float* __restrict__ cb,
                                                float* __restrict__ cc) {
#pragma clang fp contract(off)
  int i = blockIdx.x * BLK + threadIdx.x;   // [0, Q*K)
  const float* c = cb + i * D;
  float p[D];
#pragma unroll
  for (int d = 0; d < D; ++d) p[d] = c[d] * c[d];   // rounded products
  cc[i] = np_sum8_pureseq(p);
}

// ---- main ----
__global__ __launch_bounds__(BLK) void rvq_main(const float* __restrict__ x,
                                                const float* __restrict__ cb,
                                                const float* __restrict__ cct,
                                                float* __restrict__ out,
                                                double* __restrict__ partials) {
#pragma clang fp contract(off)
  __shared__ float sC[K][D];    // 32 KiB codebook (f32)
  __shared__ float sCC[K];      // 4 KiB ||c||^2
  const int tid = threadIdx.x;
  const int bt0 = blockIdx.x * (BLK * TPT) + tid;
  const int bt1 = bt0 + BLK;

  float rf[2][D];   // residual (f32, exact chain)
  float qv[2][D];   // accumulated quantized (f32)
  {
    const float4* x0 = (const float4*)(x + bt0 * D);
    const float4* x1 = (const float4*)(x + bt1 * D);
    float4 a0 = x0[0], b0 = x0[1], a1 = x1[0], b1 = x1[1];
    rf[0][0] = a0.x; rf[0][1] = a0.y; rf[0][2] = a0.z; rf[0][3] = a0.w;
    rf[0][4] = b0.x; rf[0][5] = b0.y; rf[0][6] = b0.z; rf[0][7] = b0.w;
    rf[1][0] = a1.x; rf[1][1] = a1.y; rf[1][2] = a1.z; rf[1][3] = a1.w;
    rf[1][4] = b1.x; rf[1][5] = b1.y; rf[1][6] = b1.z; rf[1][7] = b1.w;
#pragma unroll
    for (int t = 0; t < 2; ++t)
#pragma unroll
      for (int d = 0; d < D; ++d) qv[t][d] = 0.0f;
  }
  double lossAcc = 0.0;

  for (int q = 0; q < Q; ++q) {
    __syncthreads();
    {
      const float4* src = (const float4*)(cb + q * (K * D));
      float4* dst = (float4*)sC;
      for (int i = tid; i < (K * D) / 4; i += BLK) dst[i] = src[i];
      const float* ccq = cct + q * K;
      for (int i = tid; i < K; i += BLK) sCC[i] = ccq[i];
    }
    __syncthreads();

    // rr = np.sum(r*r): rounded squares, pure sequential tree
    float rr0, rr1;
    {
      float p[D];
#pragma unroll
      for (int d = 0; d < D; ++d) p[d] = rf[0][d] * rf[0][d];
      rr0 = np_sum8_pureseq(p);
#pragma unroll
      for (int d = 0; d < D; ++d) p[d] = rf[1][d] * rf[1][d];
      rr1 = np_sum8_pureseq(p);
    }

    // argmin scan: einsum SSE3 model — lanes l_i = fl(m_i+m_{i+4}),
    // dot = (l0+l1)+(l2+l3)
    float best0 = 3.402823466e+38f, best1 = 3.402823466e+38f;
    int idx0 = 0, idx1 = 0;
    for (int k = 0; k < K; ++k) {
      const float4* row = (const float4*)sC[k];
      float4 ca = row[0], cb4 = row[1];
      float c0 = ca.x, c1 = ca.y, c2 = ca.z, c3 = ca.w;
      float c4 = cb4.x, c5 = cb4.y, c6 = cb4.z, c7 = cb4.w;
      float ccv = sCC[k];

      float m0 = rf[0][0] * c0, m1 = rf[0][1] * c1, m2 = rf[0][2] * c2,
            m3 = rf[0][3] * c3, m4 = rf[0][4] * c4, m5 = rf[0][5] * c5,
            m6 = rf[0][6] * c6, m7 = rf[0][7] * c7;
      float l0 = m0 + m4, l1 = m1 + m5, l2 = m2 + m6, l3 = m3 + m7;
      float dot0 = (l0 + l1) + (l2 + l3);
      float s0 = (rr0 + ccv) - 2.0f * dot0;
      if (s0 < best0) { best0 = s0; idx0 = k; }

      float n0 = rf[1][0] * c0, n1 = rf[1][1] * c1, n2 = rf[1][2] * c2,
            n3 = rf[1][3] * c3, n4 = rf[1][4] * c4, n5 = rf[1][5] * c5,
            n6 = rf[1][6] * c6, n7 = rf[1][7] * c7;
      float j0 = n0 + n4, j1 = n1 + n5, j2 = n2 + n6, j3 = n3 + n7;
      float dot1 = (j0 + j1) + (j2 + j3);
      float s1 = (rr1 + ccv) - 2.0f * dot1;
      if (s1 < best1) { best1 = s1; idx1 = k; }
    }

    // f32 update chain (exactly-rounded elementwise ops)
#pragma unroll
    for (int d = 0; d < D; ++d) {
      float e0 = sC[idx0][d];
      qv[0][d] = qv[0][d] + e0;
      rf[0][d] = rf[0][d] - e0;
      float f0 = rf[0][d] - e0;
      lossAcc = fma((double)f0, (double)f0, lossAcc);
      float e1 = sC[idx1][d];
      qv[1][d] = qv[1][d] + e1;
      rf[1][d] = rf[1][d] - e1;
      float f1 = rf[1][d] - e1;
      lossAcc = fma((double)f1, (double)f1, lossAcc);
    }
    out[CODES_OFF + q * TOKENS + bt0] = (float)idx0;
    out[CODES_OFF + q * TOKENS + bt1] = (float)idx1;
  }

  // straight-through: out_q = f32(x + f32(q - x))
  {
    const float4* x0 = (const float4*)(x + bt0 * D);
    const float4* x1 = (const float4*)(x + bt1 * D);
    float xs[2][D];
    float4 a0 = x0[0], b0 = x0[1], a1 = x1[0], b1 = x1[1];
    xs[0][0] = a0.x; xs[0][1] = a0.y; xs[0][2] = a0.z; xs[0][3] = a0.w;
    xs[0][4] = b0.x; xs[0][5] = b0.y; xs[0][6] = b0.z; xs[0][7] = b0.w;
    xs[1][0] = a1.x; xs[1][1] = a1.y; xs[1][2] = a1.z; xs[1][3] = a1.w;
    xs[1][4] = b1.x; xs[1][5] = b1.y; xs[1][6] = b1.z; xs[1][7] = b1.w;
    float o[2][D];
#pragma unroll
    for (int t = 0; t < 2; ++t)
#pragma unroll
      for (int d = 0; d < D; ++d) o[t][d] = xs[t][d] + (qv[t][d] - xs[t][d]);
    float4 v;
    v.x = o[0][0]; v.y = o[0][1]; v.z = o[0][2]; v.w = o[0][3];
    ((float4*)(out + bt0 * D))[0] = v;
    v.x = o[0][4]; v.y = o[0][5]; v.z = o[0][6]; v.w = o[0][7];
    ((float4*)(out + bt0 * D))[1] = v;
    v.x = o[1][0]; v.y = o[1][1]; v.z = o[1][2]; v.w = o[1][3];
    ((float4*)(out + bt1 * D))[0] = v;
    v.x = o[1][4]; v.y = o[1][5]; v.z = o[1][6]; v.w = o[1][7];
    ((float4*)(out + bt1 * D))[1] = v;
  }

  // block loss reduction
  for (int off = 32; off; off >>= 1) lossAcc += __shfl_down(lossAcc, off);
  __syncthreads();
  double* red = (double*)sC;
  if ((tid & 63) == 0) red[tid >> 6] = lossAcc;
  __syncthreads();
  if (tid == 0) partials[blockIdx.x] = red[0] + red[1] + red[2] + red[3];
}

// ---- finalize loss ----
__global__ __launch_bounds__(BLK) void rvq_loss(const double* __restrict__ partials,
                                                float* __restrict__ out) {
  int tid = threadIdx.x;
  double s = partials[tid] + partials[tid + BLK];
  for (int off = 32; off; off >>= 1) s += __shfl_down(s, off);
  __shared__ double red[4];
  if ((tid & 63) == 0) red[tid >> 6] = s;
  __syncthreads();
  if (tid == 0)
    out[LOSS_OFF] = (float)((red[0] + red[1] + red[2] + red[3]) *
                            (0.25 / 2097152.0));
}

extern "C" void kernel_launch(void* const* d_in, const int* in_sizes, int n_in,
                              void* d_out, int out_size, void* d_ws, size_t ws_size,
                              hipStream_t stream) {
  const float* x  = (const float*)d_in[0];
  const float* cb = (const float*)d_in[1];
  float* out = (float*)d_out;
  double* partials = (double*)d_ws;          // GRID doubles
  float* cc = (float*)(partials + GRID);     // Q*K floats

  rvq_prep<<<(Q * K) / BLK, BLK, 0, stream>>>(cb, cc);
  rvq_main<<<GRID, BLK, 0, stream>>>(x, cb, cc, out, partials);
  rvq_loss<<<1, BLK, 0, stream>>>(partials, out);
}